// Round 25
// baseline (609.136 us; speedup 1.0000x reference)
//
#include <hip/hip_runtime.h>

#define NN 50000
#define EE 500000
#define BB 64
#define TT 50
#define FN 128
#define FS 64
#define HD 64
#define ETOT (EE + NN)
#define NPAD 50176   // 1024*49, k_scan guard-free

typedef __attribute__((ext_vector_type(8))) short short8v;
typedef __attribute__((ext_vector_type(4))) short short4v;
typedef __attribute__((ext_vector_type(4))) float f4v;

__device__ __forceinline__ float b2f(short u){
  union { unsigned int i; float f; } v; v.i = ((unsigned int)(unsigned short)u) << 16; return v.f;
}
__device__ __forceinline__ short f2b(float f){
  union { float f; unsigned int i; } v; v.f = f;
  unsigned int x = v.i;
  return (short)((x + 0x7fffu + ((x >> 16) & 1u)) >> 16);
}
__device__ __forceinline__ f4v mfma16(short8v a, short8v b, f4v c){
  return __builtin_amdgcn_mfma_f32_16x16x32_bf16(a, b, c, 0, 0, 0);
}
__device__ __forceinline__ float frcp(float x){ return __builtin_amdgcn_rcpf(x); }
__device__ __forceinline__ float fsig(float x){ return frcp(1.f + __expf(-x)); }
__device__ __forceinline__ float ftanh(float x){ return 1.f - 2.f*frcp(1.f + __expf(2.f*x)); }

constexpr int SEG_CUM[25] = {0, 6400000, 6604800, 6637568, 6637824, 6638080,
  6638336, 6654720, 6654784, 6654848, 6654912, 6671296, 6687680, 6687936,
  6688192, 6704576, 6720960, 6721216, 6721472, 6770624, 6771008, 6787392,
  6787520, 6787904, 6787906};
#define ARENA_VEC (6787904/8)

struct Ptrs { const void* p[24]; };

// ---------------- zero deg/pool/done ----------------
__global__ __launch_bounds__(256) void k_zero(int* deg, float* pool, int* done){
  int i = blockIdx.x*256 + threadIdx.x;
  deg[i] = (i < NN) ? 1 : 0;            // self loop; pad zeros (grid covers NPAD exactly)
  if (i < BB*HD) pool[i] = 0.f;
  if (i == 0) done[0] = 0;
}

// ---------------- F1: convert (blocks 0..2047) || count (blocks 2048..4001) ----------------
__global__ __launch_bounds__(256) void k_cvt(Ptrs P, short* arena, int* flag, const int* ei, int* deg){
  int bid = blockIdx.x;
  if (bid >= 2048){
    // ---- count (atomic-heavy, LAST: fills CUs as convert drains)
    int e = (bid - 2048)*256 + threadIdx.x;
    if (e < EE) atomicAdd(&deg[ei[EE + e]], 1);
    return;
  }
  __shared__ int cnt;
  if (threadIdx.x == 0) cnt = 0;
  __syncthreads();
  {
    const unsigned short* x16 = (const unsigned short*)P.p[0];
    int c = 0;
    for (int i = threadIdx.x; i < 2048; i += 256){
      unsigned short vv = x16[2*i];     // even shorts: f32 low-halves (random) vs bf16 values
      int e = (vv >> 7) & 0xFF;
      if (e >= 64 && e < 160) c++;
    }
    atomicAdd(&cnt, c);
  }
  __syncthreads();
  bool isb = (cnt >= 1536);             // 1 = inputs are bf16
  if (bid == 0 && threadIdx.x == 0) *flag = isb ? 1 : 0;

  int idx = bid*256 + threadIdx.x;
  for (int v = idx; v < ARENA_VEC; v += 2048*256){
    int i = v*8;
    int s = 0;
#pragma unroll
    for (int k = 1; k < 24; ++k) if (i >= SEG_CUM[k]) s = k;
    int j = i - SEG_CUM[s];
    short8v o;
    if (isb){
      o = *(const short8v*)((const short*)P.p[s] + j);
    } else {
      const float* f = (const float*)P.p[s] + j;
      f4v lo = *(const f4v*)f;
      f4v hi = *(const f4v*)(f + 4);
#pragma unroll
      for (int q = 0; q < 4; ++q){ o[q] = f2b(lo[q]); o[4+q] = f2b(hi[q]); }
    }
    *(short8v*)(arena + i) = o;
  }
  if (bid == 0 && threadIdx.x == 0){
    for (int j = 0; j < 2; ++j)
      arena[6787904 + j] = isb ? ((const short*)P.p[23])[j] : f2b(((const float*)P.p[23])[j]);
  }
}

// ---------------- scan: register-resident, off only ----------------
__global__ __launch_bounds__(1024) void k_scan(const int* __restrict__ deg, int* __restrict__ off){
  __shared__ int buf[1024];
  int tid = threadIdx.x;
  int start = tid*49;
  int v[49];
#pragma unroll
  for (int j = 0; j < 49; ++j) v[j] = deg[start + j];
  int s = 0;
#pragma unroll
  for (int j = 0; j < 49; ++j) s += v[j];
  buf[tid] = s;
  __syncthreads();
  for (int st = 1; st < 1024; st <<= 1){
    int t = (tid >= st) ? buf[tid - st] : 0;
    __syncthreads();
    buf[tid] += t;
    __syncthreads();
  }
  int run = buf[tid] - s;
#pragma unroll
  for (int j = 0; j < 49; ++j){
    int i = start + j;
    if (i < NN) off[i] = run;
    run += v[j];
  }
  if (tid == 1023) off[NN] = run;
}

// ---------------- self: csr self-loop + cur init (separate kernel = real barrier vs scatter) ----------------
__global__ __launch_bounds__(256) void k_self(const int* off, int* cur, int* csr){
  int v = blockIdx.x*256 + threadIdx.x;
  if (v < NN){ int o = off[v]; csr[o] = v; cur[v] = o + 1; }
}

// ---------------- F3: xp (0..99) || gemm1 (100..881) || scatter (882..2835) ----------------
__global__ __launch_bounds__(256) void k_sxg(const int* __restrict__ ei, int* __restrict__ cur, int* __restrict__ csr,
                                             const short* __restrict__ x, const short* __restrict__ W1,
                                             const short* __restrict__ as1, const short* __restrict__ ad1,
                                             short* __restrict__ h1, float* __restrict__ a1s, float* __restrict__ a1d,
                                             const short* __restrict__ seq,
                                             const short* __restrict__ WihF, const short* __restrict__ bihF, const short* __restrict__ bhhF,
                                             const short* __restrict__ WihB, const short* __restrict__ bihB, const short* __restrict__ bhhB,
                                             float* __restrict__ Xp){
  int bid = blockIdx.x;
  int l = threadIdx.x & 63;
  if (bid < 100){
    // ---- xp: Xp in permuted gate order (small, FIRST)
    int dir = bid / 50;
    int bx  = bid % 50;
    const short* Wih = dir ? WihB : WihF;
    const short* bih = dir ? bihB : bihF;
    const short* bhh = dir ? bhhB : bhhF;
    int wv = bx*4 + (threadIdx.x >> 6);
    int row = wv*16 + (l & 15);
    int koff = (l >> 4)*8;
    short8v a[2];
#pragma unroll
    for (int k = 0; k < 2; ++k) a[k] = *(const short8v*)(seq + (size_t)row*64 + k*32 + koff);
    int r0 = wv*16 + (l >> 4)*4;
    float* Xpd = Xp + (size_t)dir*TT*BB*256;
#pragma unroll
    for (int nt = 0; nt < 16; ++nt){
      f4v acc = {0.f,0.f,0.f,0.f};
#pragma unroll
      for (int k = 0; k < 2; ++k){
        short8v b = *(const short8v*)(Wih + (size_t)(nt*16 + (l & 15))*64 + k*32 + koff);
        acc = mfma16(a[k], b, acc);
      }
      int col = nt*16 + (l & 15);
      float bias = b2f(bih[col]) + b2f(bhh[col]);
      int gate = col >> 6, ch = col & 63;
      int pcol = ((ch>>5)*8 + ((ch>>4)&1)*4 + gate)*16 + (ch & 15);
#pragma unroll
      for (int r = 0; r < 4; ++r){
        int rr = r0 + r;
        int bidx = rr / TT, t = rr % TT;
        Xpd[((size_t)t*BB + bidx)*256 + pcol] = acc[r] + bias;
      }
    }
  } else if (bid < 882){
    // ---- gemm1 + fused scores (bulk compute, SECOND)
    int wv = (bid - 100)*4 + (threadIdx.x >> 6);
    if (wv >= NN/16) return;
    int row = wv*16 + (l & 15);
    int koff = (l >> 4)*8;
    short8v a[4];
#pragma unroll
    for (int k = 0; k < 4; ++k) a[k] = *(const short8v*)(x + (size_t)row*128 + k*32 + koff);
    int r0 = wv*16 + (l >> 4)*4;
    float ssA[4][4], sdA[4][4];
#pragma unroll
    for (int h = 0; h < 4; ++h)
#pragma unroll
      for (int r = 0; r < 4; ++r){ ssA[h][r] = 0.f; sdA[h][r] = 0.f; }
#pragma unroll
    for (int nt = 0; nt < 16; ++nt){
      f4v acc = {0.f,0.f,0.f,0.f};
#pragma unroll
      for (int k = 0; k < 4; ++k){
        short8v b = *(const short8v*)(W1 + (size_t)(nt*16 + (l & 15))*128 + k*32 + koff);
        acc = mfma16(a[k], b, acc);
      }
      int col = nt*16 + (l & 15);
      float asv = b2f(as1[col]), adv = b2f(ad1[col]);
      int h = nt >> 2;
#pragma unroll
      for (int r = 0; r < 4; ++r){
        h1[(size_t)(r0 + r)*256 + col] = f2b(acc[r]);
        ssA[h][r] += acc[r]*asv;
        sdA[h][r] += acc[r]*adv;
      }
    }
#pragma unroll
    for (int m = 1; m < 16; m <<= 1){
#pragma unroll
      for (int h = 0; h < 4; ++h)
#pragma unroll
        for (int r = 0; r < 4; ++r){
          ssA[h][r] += __shfl_xor(ssA[h][r], m, 64);
          sdA[h][r] += __shfl_xor(sdA[h][r], m, 64);
        }
    }
    if ((l & 15) == 0){
#pragma unroll
      for (int r = 0; r < 4; ++r){
        f4v os, od;
        os[0]=ssA[0][r]; os[1]=ssA[1][r]; os[2]=ssA[2][r]; os[3]=ssA[3][r];
        od[0]=sdA[0][r]; od[1]=sdA[1][r]; od[2]=sdA[2][r]; od[3]=sdA[3][r];
        *(f4v*)(a1s + (size_t)(r0 + r)*4) = os;
        *(f4v*)(a1d + (size_t)(r0 + r)*4) = od;
      }
    }
  } else {
    // ---- scatter (atomic-heavy, LAST: fills CUs as gemm1 drains)
    int e = (bid - 882)*256 + threadIdx.x;
    if (e < EE){
      int d = ei[EE + e];
      int pos = atomicAdd(&cur[d], 1);
      csr[pos] = ei[e];
    }
  }
}

// ---------------- F4: lstm (blocks 0..7) || fagg1 (blocks 8..12507) ----------------
union ShF4 {
  struct { int s_u[4][64]; float s_pp[4][4][64]; } agg;  // s_pp[hh][w][l]: conflict-free stores
  struct { short hl[2][16][76]; } rec;
};

__global__ __launch_bounds__(256) void k_f1ls(const int* __restrict__ off, const int* __restrict__ csr,
                                              const short* __restrict__ h1, const float* __restrict__ a1s,
                                              const float* __restrict__ a1d, const short* __restrict__ b1,
                                              short* __restrict__ g1,
                                              const float* __restrict__ Xp,
                                              const short* __restrict__ WhhF, const short* __restrict__ WhhB,
                                              short* __restrict__ lout){
  __shared__ ShF4 sh;
  int bid = blockIdx.x;
  int tid = threadIdx.x;
  int l = tid & 63;
  if (bid < 8){
    // ---- lstm FIRST (8 tiny blocks, overlaps fagg1)
    int bg = bid & 3, dir = bid >> 2;
    const short* Whh = dir ? WhhB : WhhF;
    const float* Xpd = Xp + (size_t)dir*TT*BB*256 + (size_t)bg*16*256;
    for (int i = tid; i < 16*64; i += 256) sh.rec.hl[0][i>>6][i&63] = 0;

    int w = tid >> 6;
    int c16 = l & 15;
    int koff = (l >> 4)*8;
    int r0 = (l >> 4)*4;
    int ch = (w>>1)*32 + (w&1)*16 + c16;
    short8v wb0[4], wb1[4];
#pragma unroll
    for (int j = 0; j < 4; ++j){
      int nt = w*4 + j;
      int jj = nt & 7, half = nt >> 3;
      int gate = jj & 3, chx = half*32 + (jj>>2)*16 + c16;
      int src = gate*64 + chx;
      wb0[j] = *(const short8v*)(Whh + (size_t)src*64 + koff);
      wb1[j] = *(const short8v*)(Whh + (size_t)src*64 + 32 + koff);
    }
    float creg[4] = {0.f,0.f,0.f,0.f};

    float xg[4][4];
    {
      int t0 = dir ? (TT-1) : 0;
      const float* xpb = Xpd + (size_t)t0*BB*256;
#pragma unroll
      for (int j = 0; j < 4; ++j){
        int p = (w*4 + j)*16 + c16;
#pragma unroll
        for (int r = 0; r < 4; ++r) xg[j][r] = xpb[(size_t)(r0 + r)*256 + p];
      }
    }

    int cur = 0;
    for (int s = 0; s < TT; ++s){
      int t = dir ? (TT - 1 - s) : s;
      __syncthreads();
      float xgn[4][4];
      if (s + 1 < TT){
        int tn = dir ? (TT - 2 - s) : (s + 1);
        const float* xpb = Xpd + (size_t)tn*BB*256;
#pragma unroll
        for (int j = 0; j < 4; ++j){
          int p = (w*4 + j)*16 + c16;
#pragma unroll
          for (int r = 0; r < 4; ++r) xgn[j][r] = xpb[(size_t)(r0 + r)*256 + p];
        }
      }
      short8v a0 = *(const short8v*)&sh.rec.hl[cur][c16][koff];
      short8v a1 = *(const short8v*)&sh.rec.hl[cur][c16][32 + koff];
      f4v acc[4];
#pragma unroll
      for (int j = 0; j < 4; ++j){
        f4v z = {0.f,0.f,0.f,0.f};
        z = mfma16(a0, wb0[j], z);
        z = mfma16(a1, wb1[j], z);
        acc[j] = z;
      }
      int nxt = cur ^ 1;
#pragma unroll
      for (int r = 0; r < 4; ++r){
        float gi = acc[0][r] + xg[0][r];
        float gf = acc[1][r] + xg[1][r];
        float gg = acc[2][r] + xg[2][r];
        float go = acc[3][r] + xg[3][r];
        float cn = fsig(gf)*creg[r] + fsig(gi)*ftanh(gg);
        creg[r] = cn;
        float hv = fsig(go)*ftanh(cn);
        short hb = f2b(hv);
        int row = r0 + r;
        sh.rec.hl[nxt][row][ch] = hb;
        lout[((size_t)(bg*16 + row)*TT + t)*128 + dir*64 + ch] = hb;
      }
#pragma unroll
      for (int j = 0; j < 4; ++j)
#pragma unroll
        for (int r = 0; r < 4; ++r) xg[j][r] = xgn[j][r];
      cur = nxt;
    }
  } else {
    // ---- fagg1: PhaseA lane=edge; PhaseB 2 rows/iter 16B/lane
    int v = (bid - 8)*4 + (tid >> 6);
    if (v >= NN) return;
    int w = tid >> 6;
    int rp  = l >> 5;
    int ch8 = (l & 31)*8;
    int hh  = (l & 31) >> 3;
    const f4v ad4 = *(const f4v*)(a1d + v*4);
    int e0 = off[v], e1 = off[v+1];
    float s0=0.f,s1=0.f,s2=0.f,s3=0.f;
    float acc[8] = {0.f,0.f,0.f,0.f,0.f,0.f,0.f,0.f};

    for (int base = e0; base < e1; base += 64){
      int nc = e1 - base; if (nc > 64) nc = 64;
      int u = v;
      float p0=0.f,p1=0.f,p2=0.f,p3=0.f;
      if (l < nc){
        u = csr[base + l];
        f4v as4 = *(const f4v*)(a1s + u*4);
        float t0 = as4[0]+ad4[0]; t0 = (t0>=0.f)?t0:0.2f*t0; p0 = __expf(fminf(t0,30.f));
        float t1 = as4[1]+ad4[1]; t1 = (t1>=0.f)?t1:0.2f*t1; p1 = __expf(fminf(t1,30.f));
        float t2 = as4[2]+ad4[2]; t2 = (t2>=0.f)?t2:0.2f*t2; p2 = __expf(fminf(t2,30.f));
        float t3 = as4[3]+ad4[3]; t3 = (t3>=0.f)?t3:0.2f*t3; p3 = __expf(fminf(t3,30.f));
      }
      sh.agg.s_u[w][l] = u;
      sh.agg.s_pp[0][w][l] = p0;        // plane-split: lane->bank conflict-free
      sh.agg.s_pp[1][w][l] = p1;
      sh.agg.s_pp[2][w][l] = p2;
      sh.agg.s_pp[3][w][l] = p3;
      float q0=p0,q1=p1,q2=p2,q3=p3;
#pragma unroll
      for (int st = 1; st < 64; st <<= 1){
        q0 += __shfl_xor(q0, st, 64);
        q1 += __shfl_xor(q1, st, 64);
        q2 += __shfl_xor(q2, st, 64);
        q3 += __shfl_xor(q3, st, 64);
      }
      s0 += q0; s1 += q1; s2 += q2; s3 += q3;
      asm volatile("s_waitcnt lgkmcnt(0)" ::: "memory");
      int nit = (nc + 1) >> 1;
#pragma unroll 4
      for (int i = 0; i < nit; ++i){
        int idx = i*2 + rp;
        int   ui = sh.agg.s_u[w][idx];
        float pi = sh.agg.s_pp[hh][w][idx];
        short8v hv = *(const short8v*)(h1 + (size_t)ui*256 + ch8);
#pragma unroll
        for (int j = 0; j < 8; ++j) acc[j] += pi*b2f(hv[j]);
      }
      asm volatile("s_waitcnt lgkmcnt(0)" ::: "memory");
    }
#pragma unroll
    for (int j = 0; j < 8; ++j) acc[j] += __shfl_xor(acc[j], 32, 64);
    if (l < 32){
      float mys = (hh==0)?s0:((hh==1)?s1:((hh==2)?s2:s3));
      float inv = 1.f/mys;
      short8v bb = *(const short8v*)(b1 + ch8);
      short8v o;
#pragma unroll
      for (int j = 0; j < 8; ++j) o[j] = f2b(fmaxf(acc[j]*inv + b2f(bb[j]), 0.f));
      *(short8v*)(g1 + (size_t)v*256 + ch8) = o;
    }
  }
}

// ---------------- F5: qkv (blocks 0..49) || gemm2 (blocks 50..831) ----------------
__global__ __launch_bounds__(256) void k_g2qk(const short* __restrict__ g1, const short* __restrict__ W2,
                                              const short* __restrict__ as2, const short* __restrict__ ad2,
                                              short* __restrict__ h2, float* __restrict__ a2s, float* __restrict__ a2d,
                                              const short* __restrict__ lout, const short* __restrict__ Winw,
                                              const short* __restrict__ Winb, short* __restrict__ qkv){
  int bid = blockIdx.x;
  int l = threadIdx.x & 63;
  if (bid < 50){
    int wv = bid*4 + (threadIdx.x >> 6);
    int row = wv*16 + (l & 15);
    int koff = (l >> 4)*8;
    short8v a[4];
#pragma unroll
    for (int k = 0; k < 4; ++k) a[k] = *(const short8v*)(lout + (size_t)row*128 + k*32 + koff);
    int r0 = wv*16 + (l >> 4)*4;
#pragma unroll
    for (int nt = 0; nt < 24; ++nt){
      f4v acc = {0.f,0.f,0.f,0.f};
#pragma unroll
      for (int k = 0; k < 4; ++k){
        short8v b = *(const short8v*)(Winw + (size_t)(nt*16 + (l & 15))*128 + k*32 + koff);
        acc = mfma16(a[k], b, acc);
      }
      int col = nt*16 + (l & 15);
      float bv = b2f(Winb[col]);
#pragma unroll
      for (int r = 0; r < 4; ++r) qkv[(size_t)(r0 + r)*384 + col] = f2b(acc[r] + bv);
    }
  } else {
    int wv = (bid - 50)*4 + (threadIdx.x >> 6);
    if (wv >= NN/16) return;
    int row = wv*16 + (l & 15);
    int koff = (l >> 4)*8;
    short8v a[8];
#pragma unroll
    for (int k = 0; k < 8; ++k) a[k] = *(const short8v*)(g1 + (size_t)row*256 + k*32 + koff);
    int r0 = wv*16 + (l >> 4)*4;
    float ss[4] = {0.f,0.f,0.f,0.f}, sd[4] = {0.f,0.f,0.f,0.f};
#pragma unroll
    for (int nt = 0; nt < 4; ++nt){
      f4v acc = {0.f,0.f,0.f,0.f};
#pragma unroll
      for (int k = 0; k < 8; ++k){
        short8v b = *(const short8v*)(W2 + (size_t)(nt*16 + (l & 15))*256 + k*32 + koff);
        acc = mfma16(a[k], b, acc);
      }
      int col = nt*16 + (l & 15);
      float asv = b2f(as2[col]), adv = b2f(ad2[col]);
#pragma unroll
      for (int r = 0; r < 4; ++r){
        h2[(size_t)(r0 + r)*64 + col] = f2b(acc[r]);
        ss[r] += acc[r]*asv;
        sd[r] += acc[r]*adv;
      }
    }
#pragma unroll
    for (int m = 1; m < 16; m <<= 1){
#pragma unroll
      for (int r = 0; r < 4; ++r){
        ss[r] += __shfl_xor(ss[r], m, 64);
        sd[r] += __shfl_xor(sd[r], m, 64);
      }
    }
    if ((l & 15) == 0){
#pragma unroll
      for (int r = 0; r < 4; ++r){
        a2s[r0 + r] = ss[r];
        a2d[r0 + r] = sd[r];
      }
    }
  }
}

// ---- fused alpha+gather layer 2: PhaseB 8 rows/iter, 16B/lane (standalone, 2KB LDS)
__global__ __launch_bounds__(256) void k_fagg2(const int* __restrict__ off, const int* __restrict__ csr,
                                               const short* __restrict__ h2, const float* __restrict__ a2s,
                                               const float* __restrict__ a2d, const short* __restrict__ b2,
                                               short* __restrict__ g2){
  __shared__ int   s_u[4][64];
  __shared__ float s_p[4][64];
  int v = blockIdx.x*4 + (threadIdx.x >> 6);
  if (v >= NN) return;
  int w = threadIdx.x >> 6;
  int l = threadIdx.x & 63;
  int rp  = l >> 3;
  int ch8 = (l & 7)*8;
  float adst = a2d[v];
  int e0 = off[v], e1 = off[v+1];
  float s = 0.f;
  float acc[8] = {0.f,0.f,0.f,0.f,0.f,0.f,0.f,0.f};

  for (int base = e0; base < e1; base += 64){
    int nc = e1 - base; if (nc > 64) nc = 64;
    int u = v;
    float p = 0.f;
    if (l < nc){
      u = csr[base + l];
      float t = a2s[u] + adst;
      t = (t>=0.f)?t:0.2f*t;
      p = __expf(fminf(t,30.f));
    }
    s_u[w][l] = u;
    s_p[w][l] = p;
    float q = p;
#pragma unroll
    for (int st = 1; st < 64; st <<= 1) q += __shfl_xor(q, st, 64);
    s += q;
    asm volatile("s_waitcnt lgkmcnt(0)" ::: "memory");
    int nit = (nc + 7) >> 3;
#pragma unroll 2
    for (int i = 0; i < nit; ++i){
      int idx = i*8 + rp;
      int   ui = s_u[w][idx];
      float pi = s_p[w][idx];
      short8v hv = *(const short8v*)(h2 + (size_t)ui*64 + ch8);
#pragma unroll
      for (int j = 0; j < 8; ++j) acc[j] += pi*b2f(hv[j]);
    }
    asm volatile("s_waitcnt lgkmcnt(0)" ::: "memory");
  }
#pragma unroll
  for (int m = 8; m < 64; m <<= 1)
#pragma unroll
    for (int j = 0; j < 8; ++j) acc[j] += __shfl_xor(acc[j], m, 64);
  if (l < 8){
    float inv = 1.f/s;
    short8v bb = *(const short8v*)(b2 + ch8);
    short8v o;
#pragma unroll
    for (int j = 0; j < 8; ++j) o[j] = f2b(fmaxf(acc[j]*inv + b2f(bb[j]), 0.f));
    *(short8v*)(g2 + (size_t)v*64 + ch8) = o;
  }
}

// ---------------- F6: pool (blocks 0..511) || attn (blocks 512..767) + last-block final ----------------
union ShF6 {
  struct { int seg[2]; float red[4][64]; } pl;
  struct { float kl[50][32]; float vl[50][32]; float ol[50][32]; } at;
};

__global__ __launch_bounds__(256) void k_plat(const short* __restrict__ g2, const int* __restrict__ batch,
                                              float* __restrict__ pool, float* __restrict__ cntf,
                                              const short* __restrict__ qkv, float* __restrict__ omean,
                                              const short* __restrict__ Woutw, const short* __restrict__ Woutb,
                                              const short* __restrict__ fcw, const short* __restrict__ fcb,
                                              const int* __restrict__ flag, void* __restrict__ outv,
                                              int* __restrict__ done){
  __shared__ ShF6 sh;
  __shared__ int lastv;
  __shared__ float comb[192];
  int bid = blockIdx.x;
  int tid = threadIdx.x;
  if (bid < 512){
    int split = bid & 7;
    int b = bid >> 3;
    if (tid == 0){
      int lo = 0, hi = NN;
      while (lo < hi){ int mid = (lo+hi)>>1; if (batch[mid] < b) lo = mid+1; else hi = mid; }
      sh.pl.seg[0] = lo;
      lo = 0; hi = NN;
      while (lo < hi){ int mid = (lo+hi)>>1; if (batch[mid] < b+1) lo = mid+1; else hi = mid; }
      sh.pl.seg[1] = lo;
    }
    __syncthreads();
    int lo = sh.pl.seg[0], hi = sh.pl.seg[1];
    int c = tid & 63;
    int rg = tid >> 6;
    float acc = 0.f;
    for (int r = lo + split*4 + rg; r < hi; r += 32)
      acc += b2f(g2[(size_t)r*64 + c]);
    sh.pl.red[rg][c] = acc;
    __syncthreads();
    if (tid < 64){
      float sum = sh.pl.red[0][tid] + sh.pl.red[1][tid] + sh.pl.red[2][tid] + sh.pl.red[3][tid];
      atomicAdd(&pool[b*HD + tid], sum);
    }
    if (split == 0 && tid == 0) cntf[b] = (float)(hi - lo);
  } else {
    int bb = bid - 512;
    int b = bb >> 2, h = bb & 3;
    for (int i = tid; i < 1600; i += 256){
      int t = i >> 5, c = i & 31;
      sh.at.kl[t][c] = b2f(qkv[((size_t)b*TT + t)*384 + 128 + h*32 + c]);
      sh.at.vl[t][c] = b2f(qkv[((size_t)b*TT + t)*384 + 256 + h*32 + c]);
    }
    __syncthreads();
    if (tid < TT){
      float q[32];
#pragma unroll
      for (int qq = 0; qq < 4; ++qq){
        short8v vq = *(const short8v*)(qkv + ((size_t)b*TT + tid)*384 + h*32 + qq*8);
#pragma unroll
        for (int j = 0; j < 8; ++j) q[qq*8 + j] = b2f(vq[j]);
      }
      float sc[50];
      float mx = -1e30f;
      const float scale = 0.17677669529663687f;
#pragma unroll
      for (int j = 0; j < 50; ++j){
        float d = 0.f;
#pragma unroll
        for (int c = 0; c < 32; ++c) d += q[c]*sh.at.kl[j][c];
        d *= scale;
        sc[j] = d;
        mx = fmaxf(mx, d);
      }
      float sum = 0.f;
#pragma unroll
      for (int j = 0; j < 50; ++j){ float p = __expf(sc[j] - mx); sc[j] = p; sum += p; }
      float inv = 1.f/sum;
      float o[32];
#pragma unroll
      for (int c = 0; c < 32; ++c) o[c] = 0.f;
#pragma unroll
      for (int j = 0; j < 50; ++j){
        float p = sc[j]*inv;
#pragma unroll
        for (int c = 0; c < 32; ++c) o[c] += p*sh.at.vl[j][c];
      }
#pragma unroll
      for (int c = 0; c < 32; ++c) sh.at.ol[tid][c] = o[c];
    }
    __syncthreads();
    if (tid < 32){
      float s = 0.f;
#pragma unroll
      for (int t = 0; t < TT; ++t) s += sh.at.ol[t][tid];
      omean[(size_t)b*128 + h*32 + tid] = s*0.02f;
    }
  }

  // ---- last-block fold of final (device-scope fence + ticket; no spinning)
  __syncthreads();
  __threadfence();
  if (tid == 0) lastv = (atomicAdd(done, 1) == 767) ? 1 : 0;
  __syncthreads();
  if (!lastv) return;
  __threadfence();
  for (int b2 = 0; b2 < BB; ++b2){
    if (tid < 64){
      float cnt = cntf[b2];
      comb[tid] = pool[b2*HD + tid] / fmaxf(cnt, 1.f);
    } else if (tid < 192){
      int e = tid - 64;
      float s = b2f(Woutb[e]);
      for (int j = 0; j < 128; ++j) s += omean[(size_t)b2*128 + j]*b2f(Woutw[e*128 + j]);
      comb[tid] = s;
    }
    __syncthreads();
    if (tid < 2){
      float s = b2f(fcb[tid]);
      for (int j = 0; j < 192; ++j) s += comb[j]*b2f(fcw[tid*192 + j]);
      if (*flag) ((short*)outv)[b2*2 + tid] = f2b(s);
      else       ((float*)outv)[b2*2 + tid] = s;
    }
    __syncthreads();
  }
}

extern "C" void kernel_launch(void* const* d_in, const int* in_sizes, int n_in,
                              void* d_out, int out_size, void* d_ws, size_t ws_size,
                              hipStream_t stream){
  const int* ei    = (const int*)d_in[1];
  const int* batch = (const int*)d_in[2];

  char* ws = (char*)d_ws;
  size_t o = 0;
  auto alloc = [&](size_t bytes)->char*{
    char* r = ws + o;
    o = (o + bytes + 255) & ~(size_t)255;
    return r;
  };
  short* arena = (short*)alloc((size_t)6787912*2);
  int*   flag  = (int*)alloc(256);
  char*  bufA  = alloc((size_t)NN*256*2);   // h1, later h2+g2
  char*  bufB  = alloc((size_t)NN*256*2);   // g1
  float* a1s  = (float*)alloc((size_t)NN*4*4);
  float* a1d  = (float*)alloc((size_t)NN*4*4);
  float* a2s  = (float*)alloc((size_t)NN*4);
  float* a2d  = (float*)alloc((size_t)NN*4);
  int*   deg  = (int*)alloc((size_t)NPAD*4);
  int*   offv = (int*)alloc((size_t)(NN+1)*4);
  int*   cur  = (int*)alloc((size_t)NN*4);
  int*   csr  = (int*)alloc((size_t)ETOT*4);
  float* pool = (float*)alloc((size_t)BB*HD*4);
  float* cntf = (float*)alloc((size_t)BB*4);
  float* Xp   = (float*)alloc((size_t)2*TT*BB*256*4);
  short* lout = (short*)alloc((size_t)BB*TT*128*2);
  short* qkv  = (short*)alloc((size_t)BB*TT*384*2);
  float* omean= (float*)alloc((size_t)BB*128*4);

  short* h1 = (short*)bufA;                       // [NN][256]
  short* h2 = (short*)bufA;                       // [NN][64] overlay (h1 dead after k_f1ls)
  short* g2 = (short*)(bufA + 12800000);          // [NN][64] bf16
  short* g1 = (short*)bufB;

  int* done = flag + 1;

  // arena views
  const short* xb    = arena + 0;
  const short* seqb  = arena + 6400000;
  const short* w1b   = arena + 6604800;
  const short* as1b  = arena + 6637568;
  const short* ad1b  = arena + 6637824;
  const short* b1b   = arena + 6638080;
  const short* w2b   = arena + 6638336;
  const short* as2b  = arena + 6654720;
  const short* ad2b  = arena + 6654784;
  const short* b2b   = arena + 6654848;
  const short* wihFb = arena + 6654912;
  const short* whhFb = arena + 6671296;
  const short* bihFb = arena + 6687680;
  const short* bhhFb = arena + 6687936;
  const short* wihBb = arena + 6688192;
  const short* whhBb = arena + 6704576;
  const short* bihBb = arena + 6720960;
  const short* bhhBb = arena + 6721216;
  const short* winwb = arena + 6721472;
  const short* winbb = arena + 6770624;
  const short* woutwb= arena + 6771008;
  const short* woutbb= arena + 6787392;
  const short* fcwb  = arena + 6787520;
  const short* fcbb  = arena + 6787904;

  Ptrs P;
  P.p[0]=d_in[0];  P.p[1]=d_in[3];  P.p[2]=d_in[4];  P.p[3]=d_in[5];
  P.p[4]=d_in[6];  P.p[5]=d_in[7];  P.p[6]=d_in[8];  P.p[7]=d_in[9];
  P.p[8]=d_in[10]; P.p[9]=d_in[11]; P.p[10]=d_in[12];P.p[11]=d_in[13];
  P.p[12]=d_in[14];P.p[13]=d_in[15];P.p[14]=d_in[16];P.p[15]=d_in[17];
  P.p[16]=d_in[18];P.p[17]=d_in[19];P.p[18]=d_in[20];P.p[19]=d_in[21];
  P.p[20]=d_in[22];P.p[21]=d_in[23];P.p[22]=d_in[24];P.p[23]=d_in[25];

  // zero deg/pool/done
  k_zero<<<NPAD/256, 256, 0, stream>>>(deg, pool, done);
  // F1: convert || count (count LAST)
  k_cvt<<<2048 + 1954, 256, 0, stream>>>(P, arena, flag, ei, deg);
  // scan (register-resident, off only)
  k_scan<<<1, 1024, 0, stream>>>(deg, offv);
  // self (separate kernel: real barrier before scatter reads cur)
  k_self<<<(NN+255)/256, 256, 0, stream>>>(offv, cur, csr);
  // F3: xp || gemm1 || scatter (scatter LAST)
  k_sxg<<<100 + 782 + 1954, 256, 0, stream>>>(ei, cur, csr,
                                              xb, w1b, as1b, ad1b, h1, a1s, a1d,
                                              seqb, wihFb, bihFb, bhhFb, wihBb, bihBb, bhhBb, Xp);
  // F4: lstm || fagg1
  k_f1ls<<<12508, 256, 0, stream>>>(offv, csr, h1, a1s, a1d, b1b, g1,
                                    Xp, whhFb, whhBb, lout);
  // F5: qkv || gemm2
  k_g2qk<<<832, 256, 0, stream>>>(g1, w2b, as2b, ad2b, h2, a2s, a2d,
                                  lout, winwb, winbb, qkv);
  // fagg2 (standalone, full occupancy)
  k_fagg2<<<(NN+3)/4, 256, 0, stream>>>(offv, csr, h2, a2s, a2d, b2b, g2);
  // F6: pool || attn + last-block final
  k_plat<<<768, 256, 0, stream>>>(g2, batch, pool, cntf, qkv, omean,
                                  woutwb, woutbb, fcwb, fcbb, flag, d_out, done);
}

// Round 26
// 262.864 us; speedup vs baseline: 2.3173x; 2.3173x over previous
//
#include <hip/hip_runtime.h>

#define NN 50000
#define EE 500000
#define BB 64
#define TT 50
#define FN 128
#define FS 64
#define HD 64
#define ETOT (EE + NN)
#define NPAD 50176   // 1024*49, k_scan guard-free

typedef __attribute__((ext_vector_type(8))) short short8v;
typedef __attribute__((ext_vector_type(4))) short short4v;
typedef __attribute__((ext_vector_type(4))) float f4v;

__device__ __forceinline__ float b2f(short u){
  union { unsigned int i; float f; } v; v.i = ((unsigned int)(unsigned short)u) << 16; return v.f;
}
__device__ __forceinline__ short f2b(float f){
  union { float f; unsigned int i; } v; v.f = f;
  unsigned int x = v.i;
  return (short)((x + 0x7fffu + ((x >> 16) & 1u)) >> 16);
}
__device__ __forceinline__ f4v mfma16(short8v a, short8v b, f4v c){
  return __builtin_amdgcn_mfma_f32_16x16x32_bf16(a, b, c, 0, 0, 0);
}
__device__ __forceinline__ float frcp(float x){ return __builtin_amdgcn_rcpf(x); }
__device__ __forceinline__ float fsig(float x){ return frcp(1.f + __expf(-x)); }
__device__ __forceinline__ float ftanh(float x){ return 1.f - 2.f*frcp(1.f + __expf(2.f*x)); }

constexpr int SEG_CUM[25] = {0, 6400000, 6604800, 6637568, 6637824, 6638080,
  6638336, 6654720, 6654784, 6654848, 6654912, 6671296, 6687680, 6687936,
  6688192, 6704576, 6720960, 6721216, 6721472, 6770624, 6771008, 6787392,
  6787520, 6787904, 6787906};
#define ARENA_VEC (6787904/8)

struct Ptrs { const void* p[24]; };

// ---------------- zero deg/pool ----------------
__global__ __launch_bounds__(256) void k_zero(int* deg, float* pool){
  int i = blockIdx.x*256 + threadIdx.x;
  deg[i] = (i < NN) ? 1 : 0;            // self loop; pad zeros (grid covers NPAD exactly)
  if (i < BB*HD) pool[i] = 0.f;
}

// ---------------- F1: convert (blocks 0..2047) || count (blocks 2048..4001) ----------------
__global__ __launch_bounds__(256) void k_cvt(Ptrs P, short* arena, int* flag, const int* ei, int* deg){
  int bid = blockIdx.x;
  if (bid >= 2048){
    // ---- count (atomic-heavy, LAST: fills CUs as convert drains)
    int e = (bid - 2048)*256 + threadIdx.x;
    if (e < EE) atomicAdd(&deg[ei[EE + e]], 1);
    return;
  }
  __shared__ int cnt;
  if (threadIdx.x == 0) cnt = 0;
  __syncthreads();
  {
    const unsigned short* x16 = (const unsigned short*)P.p[0];
    int c = 0;
    for (int i = threadIdx.x; i < 2048; i += 256){
      unsigned short vv = x16[2*i];     // even shorts: f32 low-halves (random) vs bf16 values
      int e = (vv >> 7) & 0xFF;
      if (e >= 64 && e < 160) c++;
    }
    atomicAdd(&cnt, c);
  }
  __syncthreads();
  bool isb = (cnt >= 1536);             // 1 = inputs are bf16
  if (bid == 0 && threadIdx.x == 0) *flag = isb ? 1 : 0;

  int idx = bid*256 + threadIdx.x;
  for (int v = idx; v < ARENA_VEC; v += 2048*256){
    int i = v*8;
    int s = 0;
#pragma unroll
    for (int k = 1; k < 24; ++k) if (i >= SEG_CUM[k]) s = k;
    int j = i - SEG_CUM[s];
    short8v o;
    if (isb){
      o = *(const short8v*)((const short*)P.p[s] + j);
    } else {
      const float* f = (const float*)P.p[s] + j;
      f4v lo = *(const f4v*)f;
      f4v hi = *(const f4v*)(f + 4);
#pragma unroll
      for (int q = 0; q < 4; ++q){ o[q] = f2b(lo[q]); o[4+q] = f2b(hi[q]); }
    }
    *(short8v*)(arena + i) = o;
  }
  if (bid == 0 && threadIdx.x == 0){
    for (int j = 0; j < 2; ++j)
      arena[6787904 + j] = isb ? ((const short*)P.p[23])[j] : f2b(((const float*)P.p[23])[j]);
  }
}

// ---------------- scan: register-resident, off only ----------------
__global__ __launch_bounds__(1024) void k_scan(const int* __restrict__ deg, int* __restrict__ off){
  __shared__ int buf[1024];
  int tid = threadIdx.x;
  int start = tid*49;
  int v[49];
#pragma unroll
  for (int j = 0; j < 49; ++j) v[j] = deg[start + j];
  int s = 0;
#pragma unroll
  for (int j = 0; j < 49; ++j) s += v[j];
  buf[tid] = s;
  __syncthreads();
  for (int st = 1; st < 1024; st <<= 1){
    int t = (tid >= st) ? buf[tid - st] : 0;
    __syncthreads();
    buf[tid] += t;
    __syncthreads();
  }
  int run = buf[tid] - s;
#pragma unroll
  for (int j = 0; j < 49; ++j){
    int i = start + j;
    if (i < NN) off[i] = run;
    run += v[j];
  }
  if (tid == 1023) off[NN] = run;
}

// ---------------- self: csr self-loop + cur init (separate kernel = real barrier vs scatter) ----------------
__global__ __launch_bounds__(256) void k_self(const int* off, int* cur, int* csr){
  int v = blockIdx.x*256 + threadIdx.x;
  if (v < NN){ int o = off[v]; csr[o] = v; cur[v] = o + 1; }
}

// ---------------- F3: xp (0..99) || gemm1 (100..881) || scatter (882..2835) ----------------
__global__ __launch_bounds__(256) void k_sxg(const int* __restrict__ ei, int* __restrict__ cur, int* __restrict__ csr,
                                             const short* __restrict__ x, const short* __restrict__ W1,
                                             const short* __restrict__ as1, const short* __restrict__ ad1,
                                             short* __restrict__ h1, float* __restrict__ a1s, float* __restrict__ a1d,
                                             const short* __restrict__ seq,
                                             const short* __restrict__ WihF, const short* __restrict__ bihF, const short* __restrict__ bhhF,
                                             const short* __restrict__ WihB, const short* __restrict__ bihB, const short* __restrict__ bhhB,
                                             float* __restrict__ Xp){
  int bid = blockIdx.x;
  int l = threadIdx.x & 63;
  if (bid < 100){
    // ---- xp: Xp in permuted gate order (small, FIRST)
    int dir = bid / 50;
    int bx  = bid % 50;
    const short* Wih = dir ? WihB : WihF;
    const short* bih = dir ? bihB : bihF;
    const short* bhh = dir ? bhhB : bhhF;
    int wv = bx*4 + (threadIdx.x >> 6);
    int row = wv*16 + (l & 15);
    int koff = (l >> 4)*8;
    short8v a[2];
#pragma unroll
    for (int k = 0; k < 2; ++k) a[k] = *(const short8v*)(seq + (size_t)row*64 + k*32 + koff);
    int r0 = wv*16 + (l >> 4)*4;
    float* Xpd = Xp + (size_t)dir*TT*BB*256;
#pragma unroll
    for (int nt = 0; nt < 16; ++nt){
      f4v acc = {0.f,0.f,0.f,0.f};
#pragma unroll
      for (int k = 0; k < 2; ++k){
        short8v b = *(const short8v*)(Wih + (size_t)(nt*16 + (l & 15))*64 + k*32 + koff);
        acc = mfma16(a[k], b, acc);
      }
      int col = nt*16 + (l & 15);
      float bias = b2f(bih[col]) + b2f(bhh[col]);
      int gate = col >> 6, ch = col & 63;
      int pcol = ((ch>>5)*8 + ((ch>>4)&1)*4 + gate)*16 + (ch & 15);
#pragma unroll
      for (int r = 0; r < 4; ++r){
        int rr = r0 + r;
        int bidx = rr / TT, t = rr % TT;
        Xpd[((size_t)t*BB + bidx)*256 + pcol] = acc[r] + bias;
      }
    }
  } else if (bid < 882){
    // ---- gemm1 + fused scores (bulk compute, SECOND)
    int wv = (bid - 100)*4 + (threadIdx.x >> 6);
    if (wv >= NN/16) return;
    int row = wv*16 + (l & 15);
    int koff = (l >> 4)*8;
    short8v a[4];
#pragma unroll
    for (int k = 0; k < 4; ++k) a[k] = *(const short8v*)(x + (size_t)row*128 + k*32 + koff);
    int r0 = wv*16 + (l >> 4)*4;
    float ssA[4][4], sdA[4][4];
#pragma unroll
    for (int h = 0; h < 4; ++h)
#pragma unroll
      for (int r = 0; r < 4; ++r){ ssA[h][r] = 0.f; sdA[h][r] = 0.f; }
#pragma unroll
    for (int nt = 0; nt < 16; ++nt){
      f4v acc = {0.f,0.f,0.f,0.f};
#pragma unroll
      for (int k = 0; k < 4; ++k){
        short8v b = *(const short8v*)(W1 + (size_t)(nt*16 + (l & 15))*128 + k*32 + koff);
        acc = mfma16(a[k], b, acc);
      }
      int col = nt*16 + (l & 15);
      float asv = b2f(as1[col]), adv = b2f(ad1[col]);
      int h = nt >> 2;
#pragma unroll
      for (int r = 0; r < 4; ++r){
        h1[(size_t)(r0 + r)*256 + col] = f2b(acc[r]);
        ssA[h][r] += acc[r]*asv;
        sdA[h][r] += acc[r]*adv;
      }
    }
#pragma unroll
    for (int m = 1; m < 16; m <<= 1){
#pragma unroll
      for (int h = 0; h < 4; ++h)
#pragma unroll
        for (int r = 0; r < 4; ++r){
          ssA[h][r] += __shfl_xor(ssA[h][r], m, 64);
          sdA[h][r] += __shfl_xor(sdA[h][r], m, 64);
        }
    }
    if ((l & 15) == 0){
#pragma unroll
      for (int r = 0; r < 4; ++r){
        f4v os, od;
        os[0]=ssA[0][r]; os[1]=ssA[1][r]; os[2]=ssA[2][r]; os[3]=ssA[3][r];
        od[0]=sdA[0][r]; od[1]=sdA[1][r]; od[2]=sdA[2][r]; od[3]=sdA[3][r];
        *(f4v*)(a1s + (size_t)(r0 + r)*4) = os;
        *(f4v*)(a1d + (size_t)(r0 + r)*4) = od;
      }
    }
  } else {
    // ---- scatter (atomic-heavy, LAST: fills CUs as gemm1 drains)
    int e = (bid - 882)*256 + threadIdx.x;
    if (e < EE){
      int d = ei[EE + e];
      int pos = atomicAdd(&cur[d], 1);
      csr[pos] = ei[e];
    }
  }
}

// ---------------- F4: lstm (blocks 0..7) || fagg1 (blocks 8..12507) ----------------
union ShF4 {
  struct { int s_u[4][64]; float s_pp[4][4][64]; } agg;  // s_pp[hh][w][l]: conflict-free stores
  struct { short hl[2][16][76]; } rec;
};

__global__ __launch_bounds__(256) void k_f1ls(const int* __restrict__ off, const int* __restrict__ csr,
                                              const short* __restrict__ h1, const float* __restrict__ a1s,
                                              const float* __restrict__ a1d, const short* __restrict__ b1,
                                              short* __restrict__ g1,
                                              const float* __restrict__ Xp,
                                              const short* __restrict__ WhhF, const short* __restrict__ WhhB,
                                              short* __restrict__ lout){
  __shared__ ShF4 sh;
  int bid = blockIdx.x;
  int tid = threadIdx.x;
  int l = tid & 63;
  if (bid < 8){
    // ---- lstm FIRST (8 tiny blocks, overlaps fagg1)
    int bg = bid & 3, dir = bid >> 2;
    const short* Whh = dir ? WhhB : WhhF;
    const float* Xpd = Xp + (size_t)dir*TT*BB*256 + (size_t)bg*16*256;
    for (int i = tid; i < 16*64; i += 256) sh.rec.hl[0][i>>6][i&63] = 0;

    int w = tid >> 6;
    int c16 = l & 15;
    int koff = (l >> 4)*8;
    int r0 = (l >> 4)*4;
    int ch = (w>>1)*32 + (w&1)*16 + c16;
    short8v wb0[4], wb1[4];
#pragma unroll
    for (int j = 0; j < 4; ++j){
      int nt = w*4 + j;
      int jj = nt & 7, half = nt >> 3;
      int gate = jj & 3, chx = half*32 + (jj>>2)*16 + c16;
      int src = gate*64 + chx;
      wb0[j] = *(const short8v*)(Whh + (size_t)src*64 + koff);
      wb1[j] = *(const short8v*)(Whh + (size_t)src*64 + 32 + koff);
    }
    float creg[4] = {0.f,0.f,0.f,0.f};

    float xg[4][4];
    {
      int t0 = dir ? (TT-1) : 0;
      const float* xpb = Xpd + (size_t)t0*BB*256;
#pragma unroll
      for (int j = 0; j < 4; ++j){
        int p = (w*4 + j)*16 + c16;
#pragma unroll
        for (int r = 0; r < 4; ++r) xg[j][r] = xpb[(size_t)(r0 + r)*256 + p];
      }
    }

    int cur = 0;
    for (int s = 0; s < TT; ++s){
      int t = dir ? (TT - 1 - s) : s;
      __syncthreads();
      float xgn[4][4];
      if (s + 1 < TT){
        int tn = dir ? (TT - 2 - s) : (s + 1);
        const float* xpb = Xpd + (size_t)tn*BB*256;
#pragma unroll
        for (int j = 0; j < 4; ++j){
          int p = (w*4 + j)*16 + c16;
#pragma unroll
          for (int r = 0; r < 4; ++r) xgn[j][r] = xpb[(size_t)(r0 + r)*256 + p];
        }
      }
      short8v a0 = *(const short8v*)&sh.rec.hl[cur][c16][koff];
      short8v a1 = *(const short8v*)&sh.rec.hl[cur][c16][32 + koff];
      f4v acc[4];
#pragma unroll
      for (int j = 0; j < 4; ++j){
        f4v z = {0.f,0.f,0.f,0.f};
        z = mfma16(a0, wb0[j], z);
        z = mfma16(a1, wb1[j], z);
        acc[j] = z;
      }
      int nxt = cur ^ 1;
#pragma unroll
      for (int r = 0; r < 4; ++r){
        float gi = acc[0][r] + xg[0][r];
        float gf = acc[1][r] + xg[1][r];
        float gg = acc[2][r] + xg[2][r];
        float go = acc[3][r] + xg[3][r];
        float cn = fsig(gf)*creg[r] + fsig(gi)*ftanh(gg);
        creg[r] = cn;
        float hv = fsig(go)*ftanh(cn);
        short hb = f2b(hv);
        int row = r0 + r;
        sh.rec.hl[nxt][row][ch] = hb;
        lout[((size_t)(bg*16 + row)*TT + t)*128 + dir*64 + ch] = hb;
      }
#pragma unroll
      for (int j = 0; j < 4; ++j)
#pragma unroll
        for (int r = 0; r < 4; ++r) xg[j][r] = xgn[j][r];
      cur = nxt;
    }
  } else {
    // ---- fagg1: PhaseA lane=edge; PhaseB 2 rows/iter 16B/lane
    int v = (bid - 8)*4 + (tid >> 6);
    if (v >= NN) return;
    int w = tid >> 6;
    int rp  = l >> 5;
    int ch8 = (l & 31)*8;
    int hh  = (l & 31) >> 3;
    const f4v ad4 = *(const f4v*)(a1d + v*4);
    int e0 = off[v], e1 = off[v+1];
    float s0=0.f,s1=0.f,s2=0.f,s3=0.f;
    float acc[8] = {0.f,0.f,0.f,0.f,0.f,0.f,0.f,0.f};

    for (int base = e0; base < e1; base += 64){
      int nc = e1 - base; if (nc > 64) nc = 64;
      int u = v;
      float p0=0.f,p1=0.f,p2=0.f,p3=0.f;
      if (l < nc){
        u = csr[base + l];
        f4v as4 = *(const f4v*)(a1s + u*4);
        float t0 = as4[0]+ad4[0]; t0 = (t0>=0.f)?t0:0.2f*t0; p0 = __expf(fminf(t0,30.f));
        float t1 = as4[1]+ad4[1]; t1 = (t1>=0.f)?t1:0.2f*t1; p1 = __expf(fminf(t1,30.f));
        float t2 = as4[2]+ad4[2]; t2 = (t2>=0.f)?t2:0.2f*t2; p2 = __expf(fminf(t2,30.f));
        float t3 = as4[3]+ad4[3]; t3 = (t3>=0.f)?t3:0.2f*t3; p3 = __expf(fminf(t3,30.f));
      }
      sh.agg.s_u[w][l] = u;
      sh.agg.s_pp[0][w][l] = p0;        // plane-split: lane->bank conflict-free
      sh.agg.s_pp[1][w][l] = p1;
      sh.agg.s_pp[2][w][l] = p2;
      sh.agg.s_pp[3][w][l] = p3;
      float q0=p0,q1=p1,q2=p2,q3=p3;
#pragma unroll
      for (int st = 1; st < 64; st <<= 1){
        q0 += __shfl_xor(q0, st, 64);
        q1 += __shfl_xor(q1, st, 64);
        q2 += __shfl_xor(q2, st, 64);
        q3 += __shfl_xor(q3, st, 64);
      }
      s0 += q0; s1 += q1; s2 += q2; s3 += q3;
      asm volatile("s_waitcnt lgkmcnt(0)" ::: "memory");
      int nit = (nc + 1) >> 1;
#pragma unroll 4
      for (int i = 0; i < nit; ++i){
        int idx = i*2 + rp;
        int   ui = sh.agg.s_u[w][idx];
        float pi = sh.agg.s_pp[hh][w][idx];
        short8v hv = *(const short8v*)(h1 + (size_t)ui*256 + ch8);
#pragma unroll
        for (int j = 0; j < 8; ++j) acc[j] += pi*b2f(hv[j]);
      }
      asm volatile("s_waitcnt lgkmcnt(0)" ::: "memory");
    }
#pragma unroll
    for (int j = 0; j < 8; ++j) acc[j] += __shfl_xor(acc[j], 32, 64);
    if (l < 32){
      float mys = (hh==0)?s0:((hh==1)?s1:((hh==2)?s2:s3));
      float inv = 1.f/mys;
      short8v bb = *(const short8v*)(b1 + ch8);
      short8v o;
#pragma unroll
      for (int j = 0; j < 8; ++j) o[j] = f2b(fmaxf(acc[j]*inv + b2f(bb[j]), 0.f));
      *(short8v*)(g1 + (size_t)v*256 + ch8) = o;
    }
  }
}

// ---------------- F5: qkv (blocks 0..49) || gemm2 (blocks 50..831) ----------------
__global__ __launch_bounds__(256) void k_g2qk(const short* __restrict__ g1, const short* __restrict__ W2,
                                              const short* __restrict__ as2, const short* __restrict__ ad2,
                                              short* __restrict__ h2, float* __restrict__ a2s, float* __restrict__ a2d,
                                              const short* __restrict__ lout, const short* __restrict__ Winw,
                                              const short* __restrict__ Winb, short* __restrict__ qkv){
  int bid = blockIdx.x;
  int l = threadIdx.x & 63;
  if (bid < 50){
    int wv = bid*4 + (threadIdx.x >> 6);
    int row = wv*16 + (l & 15);
    int koff = (l >> 4)*8;
    short8v a[4];
#pragma unroll
    for (int k = 0; k < 4; ++k) a[k] = *(const short8v*)(lout + (size_t)row*128 + k*32 + koff);
    int r0 = wv*16 + (l >> 4)*4;
#pragma unroll
    for (int nt = 0; nt < 24; ++nt){
      f4v acc = {0.f,0.f,0.f,0.f};
#pragma unroll
      for (int k = 0; k < 4; ++k){
        short8v b = *(const short8v*)(Winw + (size_t)(nt*16 + (l & 15))*128 + k*32 + koff);
        acc = mfma16(a[k], b, acc);
      }
      int col = nt*16 + (l & 15);
      float bv = b2f(Winb[col]);
#pragma unroll
      for (int r = 0; r < 4; ++r) qkv[(size_t)(r0 + r)*384 + col] = f2b(acc[r] + bv);
    }
  } else {
    int wv = (bid - 50)*4 + (threadIdx.x >> 6);
    if (wv >= NN/16) return;
    int row = wv*16 + (l & 15);
    int koff = (l >> 4)*8;
    short8v a[8];
#pragma unroll
    for (int k = 0; k < 8; ++k) a[k] = *(const short8v*)(g1 + (size_t)row*256 + k*32 + koff);
    int r0 = wv*16 + (l >> 4)*4;
    float ss[4] = {0.f,0.f,0.f,0.f}, sd[4] = {0.f,0.f,0.f,0.f};
#pragma unroll
    for (int nt = 0; nt < 4; ++nt){
      f4v acc = {0.f,0.f,0.f,0.f};
#pragma unroll
      for (int k = 0; k < 8; ++k){
        short8v b = *(const short8v*)(W2 + (size_t)(nt*16 + (l & 15))*256 + k*32 + koff);
        acc = mfma16(a[k], b, acc);
      }
      int col = nt*16 + (l & 15);
      float asv = b2f(as2[col]), adv = b2f(ad2[col]);
#pragma unroll
      for (int r = 0; r < 4; ++r){
        h2[(size_t)(r0 + r)*64 + col] = f2b(acc[r]);
        ss[r] += acc[r]*asv;
        sd[r] += acc[r]*adv;
      }
    }
#pragma unroll
    for (int m = 1; m < 16; m <<= 1){
#pragma unroll
      for (int r = 0; r < 4; ++r){
        ss[r] += __shfl_xor(ss[r], m, 64);
        sd[r] += __shfl_xor(sd[r], m, 64);
      }
    }
    if ((l & 15) == 0){
#pragma unroll
      for (int r = 0; r < 4; ++r){
        a2s[r0 + r] = ss[r];
        a2d[r0 + r] = sd[r];
      }
    }
  }
}

// ---- fused alpha+gather layer 2: PhaseB 8 rows/iter, 16B/lane
__global__ __launch_bounds__(256) void k_fagg2(const int* __restrict__ off, const int* __restrict__ csr,
                                               const short* __restrict__ h2, const float* __restrict__ a2s,
                                               const float* __restrict__ a2d, const short* __restrict__ b2,
                                               short* __restrict__ g2){
  __shared__ int   s_u[4][64];
  __shared__ float s_p[4][64];
  int v = blockIdx.x*4 + (threadIdx.x >> 6);
  if (v >= NN) return;
  int w = threadIdx.x >> 6;
  int l = threadIdx.x & 63;
  int rp  = l >> 3;
  int ch8 = (l & 7)*8;
  float adst = a2d[v];
  int e0 = off[v], e1 = off[v+1];
  float s = 0.f;
  float acc[8] = {0.f,0.f,0.f,0.f,0.f,0.f,0.f,0.f};

  for (int base = e0; base < e1; base += 64){
    int nc = e1 - base; if (nc > 64) nc = 64;
    int u = v;
    float p = 0.f;
    if (l < nc){
      u = csr[base + l];
      float t = a2s[u] + adst;
      t = (t>=0.f)?t:0.2f*t;
      p = __expf(fminf(t,30.f));
    }
    s_u[w][l] = u;
    s_p[w][l] = p;
    float q = p;
#pragma unroll
    for (int st = 1; st < 64; st <<= 1) q += __shfl_xor(q, st, 64);
    s += q;
    asm volatile("s_waitcnt lgkmcnt(0)" ::: "memory");
    int nit = (nc + 7) >> 3;
#pragma unroll 2
    for (int i = 0; i < nit; ++i){
      int idx = i*8 + rp;
      int   ui = s_u[w][idx];
      float pi = s_p[w][idx];
      short8v hv = *(const short8v*)(h2 + (size_t)ui*64 + ch8);
#pragma unroll
      for (int j = 0; j < 8; ++j) acc[j] += pi*b2f(hv[j]);
    }
    asm volatile("s_waitcnt lgkmcnt(0)" ::: "memory");
  }
#pragma unroll
  for (int m = 8; m < 64; m <<= 1)
#pragma unroll
    for (int j = 0; j < 8; ++j) acc[j] += __shfl_xor(acc[j], m, 64);
  if (l < 8){
    float inv = 1.f/s;
    short8v bb = *(const short8v*)(b2 + ch8);
    short8v o;
#pragma unroll
    for (int j = 0; j < 8; ++j) o[j] = f2b(fmaxf(acc[j]*inv + b2f(bb[j]), 0.f));
    *(short8v*)(g2 + (size_t)v*64 + ch8) = o;
  }
}

// ---------------- F6: pool (blocks 0..511) || attn (blocks 512..767) ----------------
union ShF6 {
  struct { int seg[2]; float red[4][64]; } pl;
  struct { float kl[50][32]; float vl[50][32]; float ol[50][32]; } at;
};

__global__ __launch_bounds__(256) void k_plat(const short* __restrict__ g2, const int* __restrict__ batch,
                                              float* __restrict__ pool, float* __restrict__ cntf,
                                              const short* __restrict__ qkv, float* __restrict__ omean){
  __shared__ ShF6 sh;
  int bid = blockIdx.x;
  int tid = threadIdx.x;
  if (bid < 512){
    int split = bid & 7;
    int b = bid >> 3;
    if (tid == 0){
      int lo = 0, hi = NN;
      while (lo < hi){ int mid = (lo+hi)>>1; if (batch[mid] < b) lo = mid+1; else hi = mid; }
      sh.pl.seg[0] = lo;
      lo = 0; hi = NN;
      while (lo < hi){ int mid = (lo+hi)>>1; if (batch[mid] < b+1) lo = mid+1; else hi = mid; }
      sh.pl.seg[1] = lo;
    }
    __syncthreads();
    int lo = sh.pl.seg[0], hi = sh.pl.seg[1];
    int c = tid & 63;
    int rg = tid >> 6;
    float acc = 0.f;
    for (int r = lo + split*4 + rg; r < hi; r += 32)
      acc += b2f(g2[(size_t)r*64 + c]);
    sh.pl.red[rg][c] = acc;
    __syncthreads();
    if (tid < 64){
      float sum = sh.pl.red[0][tid] + sh.pl.red[1][tid] + sh.pl.red[2][tid] + sh.pl.red[3][tid];
      atomicAdd(&pool[b*HD + tid], sum);
    }
    if (split == 0 && tid == 0) cntf[b] = (float)(hi - lo);
  } else {
    int bb = bid - 512;
    int b = bb >> 2, h = bb & 3;
    for (int i = tid; i < 1600; i += 256){
      int t = i >> 5, c = i & 31;
      sh.at.kl[t][c] = b2f(qkv[((size_t)b*TT + t)*384 + 128 + h*32 + c]);
      sh.at.vl[t][c] = b2f(qkv[((size_t)b*TT + t)*384 + 256 + h*32 + c]);
    }
    __syncthreads();
    if (tid < TT){
      float q[32];
#pragma unroll
      for (int qq = 0; qq < 4; ++qq){
        short8v vq = *(const short8v*)(qkv + ((size_t)b*TT + tid)*384 + h*32 + qq*8);
#pragma unroll
        for (int j = 0; j < 8; ++j) q[qq*8 + j] = b2f(vq[j]);
      }
      float sc[50];
      float mx = -1e30f;
      const float scale = 0.17677669529663687f;
#pragma unroll
      for (int j = 0; j < 50; ++j){
        float d = 0.f;
#pragma unroll
        for (int c = 0; c < 32; ++c) d += q[c]*sh.at.kl[j][c];
        d *= scale;
        sc[j] = d;
        mx = fmaxf(mx, d);
      }
      float sum = 0.f;
#pragma unroll
      for (int j = 0; j < 50; ++j){ float p = __expf(sc[j] - mx); sc[j] = p; sum += p; }
      float inv = 1.f/sum;
      float o[32];
#pragma unroll
      for (int c = 0; c < 32; ++c) o[c] = 0.f;
#pragma unroll
      for (int j = 0; j < 50; ++j){
        float p = sc[j]*inv;
#pragma unroll
        for (int c = 0; c < 32; ++c) o[c] += p*sh.at.vl[j][c];
      }
#pragma unroll
      for (int c = 0; c < 32; ++c) sh.at.ol[tid][c] = o[c];
    }
    __syncthreads();
    if (tid < 32){
      float s = 0.f;
#pragma unroll
      for (int t = 0; t < TT; ++t) s += sh.at.ol[t][tid];
      omean[(size_t)b*128 + h*32 + tid] = s*0.02f;
    }
  }
}

// final: combined = [pool/cnt (64), omean @ Wout^T + bout (128)]; out = combined @ fc^T + fcb
__global__ __launch_bounds__(192) void k_final(const float* __restrict__ pool, const float* __restrict__ cntf,
                                               const float* __restrict__ omean,
                                               const short* __restrict__ Woutw, const short* __restrict__ Woutb,
                                               const short* __restrict__ fcw, const short* __restrict__ fcb,
                                               const int* __restrict__ flag, void* __restrict__ outv){
  int b = blockIdx.x;
  int tid = threadIdx.x;
  __shared__ float comb[192];
  if (tid < 64){
    float cnt = cntf[b];
    comb[tid] = pool[b*HD + tid] / fmaxf(cnt, 1.f);
  } else {
    int e = tid - 64;
    float s = b2f(Woutb[e]);
    for (int j = 0; j < 128; ++j) s += omean[(size_t)b*128 + j]*b2f(Woutw[e*128 + j]);
    comb[tid] = s;
  }
  __syncthreads();
  if (tid < 2){
    float s = b2f(fcb[tid]);
    for (int j = 0; j < 192; ++j) s += comb[j]*b2f(fcw[tid*192 + j]);
    if (*flag) ((short*)outv)[b*2 + tid] = f2b(s);
    else       ((float*)outv)[b*2 + tid] = s;
  }
}

extern "C" void kernel_launch(void* const* d_in, const int* in_sizes, int n_in,
                              void* d_out, int out_size, void* d_ws, size_t ws_size,
                              hipStream_t stream){
  const int* ei    = (const int*)d_in[1];
  const int* batch = (const int*)d_in[2];

  char* ws = (char*)d_ws;
  size_t o = 0;
  auto alloc = [&](size_t bytes)->char*{
    char* r = ws + o;
    o = (o + bytes + 255) & ~(size_t)255;
    return r;
  };
  short* arena = (short*)alloc((size_t)6787912*2);
  int*   flag  = (int*)alloc(256);
  char*  bufA  = alloc((size_t)NN*256*2);   // h1, later h2+g2
  char*  bufB  = alloc((size_t)NN*256*2);   // g1
  float* a1s  = (float*)alloc((size_t)NN*4*4);
  float* a1d  = (float*)alloc((size_t)NN*4*4);
  float* a2s  = (float*)alloc((size_t)NN*4);
  float* a2d  = (float*)alloc((size_t)NN*4);
  int*   deg  = (int*)alloc((size_t)NPAD*4);
  int*   offv = (int*)alloc((size_t)(NN+1)*4);
  int*   cur  = (int*)alloc((size_t)NN*4);
  int*   csr  = (int*)alloc((size_t)ETOT*4);
  float* pool = (float*)alloc((size_t)BB*HD*4);
  float* cntf = (float*)alloc((size_t)BB*4);
  float* Xp   = (float*)alloc((size_t)2*TT*BB*256*4);
  short* lout = (short*)alloc((size_t)BB*TT*128*2);
  short* qkv  = (short*)alloc((size_t)BB*TT*384*2);
  float* omean= (float*)alloc((size_t)BB*128*4);

  short* h1 = (short*)bufA;                       // [NN][256]
  short* h2 = (short*)bufA;                       // [NN][64] overlay (h1 dead after k_f1ls)
  short* g2 = (short*)(bufA + 12800000);          // [NN][64] bf16
  short* g1 = (short*)bufB;

  // arena views
  const short* xb    = arena + 0;
  const short* seqb  = arena + 6400000;
  const short* w1b   = arena + 6604800;
  const short* as1b  = arena + 6637568;
  const short* ad1b  = arena + 6637824;
  const short* b1b   = arena + 6638080;
  const short* w2b   = arena + 6638336;
  const short* as2b  = arena + 6654720;
  const short* ad2b  = arena + 6654784;
  const short* b2b   = arena + 6654848;
  const short* wihFb = arena + 6654912;
  const short* whhFb = arena + 6671296;
  const short* bihFb = arena + 6687680;
  const short* bhhFb = arena + 6687936;
  const short* wihBb = arena + 6688192;
  const short* whhBb = arena + 6704576;
  const short* bihBb = arena + 6720960;
  const short* bhhBb = arena + 6721216;
  const short* winwb = arena + 6721472;
  const short* winbb = arena + 6770624;
  const short* woutwb= arena + 6771008;
  const short* woutbb= arena + 6787392;
  const short* fcwb  = arena + 6787520;
  const short* fcbb  = arena + 6787904;

  Ptrs P;
  P.p[0]=d_in[0];  P.p[1]=d_in[3];  P.p[2]=d_in[4];  P.p[3]=d_in[5];
  P.p[4]=d_in[6];  P.p[5]=d_in[7];  P.p[6]=d_in[8];  P.p[7]=d_in[9];
  P.p[8]=d_in[10]; P.p[9]=d_in[11]; P.p[10]=d_in[12];P.p[11]=d_in[13];
  P.p[12]=d_in[14];P.p[13]=d_in[15];P.p[14]=d_in[16];P.p[15]=d_in[17];
  P.p[16]=d_in[18];P.p[17]=d_in[19];P.p[18]=d_in[20];P.p[19]=d_in[21];
  P.p[20]=d_in[22];P.p[21]=d_in[23];P.p[22]=d_in[24];P.p[23]=d_in[25];

  // zero deg/pool
  k_zero<<<NPAD/256, 256, 0, stream>>>(deg, pool);
  // F1: convert || count (count LAST)
  k_cvt<<<2048 + 1954, 256, 0, stream>>>(P, arena, flag, ei, deg);
  // scan (register-resident, off only)
  k_scan<<<1, 1024, 0, stream>>>(deg, offv);
  // self (separate kernel: real barrier before scatter reads cur)
  k_self<<<(NN+255)/256, 256, 0, stream>>>(offv, cur, csr);
  // F3: xp || gemm1 || scatter (scatter LAST)
  k_sxg<<<100 + 782 + 1954, 256, 0, stream>>>(ei, cur, csr,
                                              xb, w1b, as1b, ad1b, h1, a1s, a1d,
                                              seqb, wihFb, bihFb, bhhFb, wihBb, bihBb, bhhBb, Xp);
  // F4: lstm || fagg1
  k_f1ls<<<12508, 256, 0, stream>>>(offv, csr, h1, a1s, a1d, b1b, g1,
                                    Xp, whhFb, whhBb, lout);
  // F5: qkv || gemm2
  k_g2qk<<<832, 256, 0, stream>>>(g1, w2b, as2b, ad2b, h2, a2s, a2d,
                                  lout, winwb, winbb, qkv);
  // GAT2 aggregate
  k_fagg2<<<(NN+3)/4, 256, 0, stream>>>(offv, csr, h2, a2s, a2d, b2b, g2);
  // F6: pool || attn
  k_plat<<<768, 256, 0, stream>>>(g2, batch, pool, cntf, qkv, omean);
  // final
  k_final<<<BB, 192, 0, stream>>>(pool, cntf, omean, woutwb, woutbb, fcwb, fcbb, flag, d_out);
}